// Round 9
// baseline (120.693 us; speedup 1.0000x reference)
//
#include <hip/hip_runtime.h>
#include <hip/hip_fp16.h>

// HyperbolicAggregation: out = proj(expmap0(A @ x, c=1), c=1)
// A sparse (rows sorted), x [50000,128] f32.
// Kernel 0: convert x f32 -> f16 into d_ws (halves gather traffic).
// Kernel 1: O(E) coalesced row_ptr build -> d_ws.
// Kernel 2: one wave per node. Per <=64-edge chunk the wave stages cols/vals
//           into its own LDS slice (one coalesced load), then reads per-edge
//           scalars from LDS. Lanes 0-31 do even edges, 32-63 odd; 8-B f16x4
//           gathers, ladder 16/8/2/1 edges (8/4/1 gathers in flight per half).

#define MIN_NORM 1e-15f
#define PROJ_EPS 4e-3f

#define LDNT(p) __builtin_nontemporal_load(p)

typedef float floatx4 __attribute__((ext_vector_type(4)));

__device__ inline float h2f(unsigned short u) {
    __half h;
    __builtin_memcpy(&h, &u, sizeof(h));
    return __half2float(h);
}

__global__ __launch_bounds__(256) void cvt_f32_to_f16(
    const float4* __restrict__ x4, uint2* __restrict__ xh, int n4)
{
    int i = blockIdx.x * blockDim.x + threadIdx.x;
    if (i >= n4) return;
    float4 a = x4[i];
    __half2 lo = __floats2half2_rn(a.x, a.y);
    __half2 hi = __floats2half2_rn(a.z, a.w);
    uint2 o;
    o.x = *reinterpret_cast<unsigned int*>(&lo);
    o.y = *reinterpret_cast<unsigned int*>(&hi);
    xh[i] = o;
}

__global__ __launch_bounds__(256) void build_rowptr_kernel(
    const int* __restrict__ rows, int* __restrict__ row_ptr,
    int n_nodes, int n_edges)
{
    int e = blockIdx.x * blockDim.x + threadIdx.x;
    if (e >= n_edges) return;
    int r = rows[e];
    int prev = (e == 0) ? -1 : rows[e - 1];
    for (int node = prev + 1; node <= r; ++node) row_ptr[node] = e;
    if (e == n_edges - 1) {
        for (int node = r + 1; node <= n_nodes; ++node) row_ptr[node] = n_edges;
    }
}

// MODE 0: f16 x (ws) + row_ptr.  MODE 2: f32 x + inline binary search (fallback).
template <int MODE>
__global__ __launch_bounds__(256) void hyp_agg_kernel(
    const float* __restrict__ xf,
    const ushort4* __restrict__ xh,
    const float* __restrict__ vals,
    const int* __restrict__ rows,
    const int* __restrict__ cols,
    const int* __restrict__ row_ptr,
    float* __restrict__ out,
    int n_nodes, int n_edges)
{
    __shared__ int   s_c[4][64];
    __shared__ float s_v[4][64];

    const int tid  = threadIdx.x;
    const int node = (int)((blockIdx.x * blockDim.x + tid) >> 6);
    if (node >= n_nodes) return;
    const int wv   = tid >> 6;     // wave within block (own LDS slice)
    const int lane = tid & 63;
    const int half = lane >> 5;    // 0: even edges of pair, 1: odd
    const int l32  = lane & 31;    // 8B (f16x4) / 16B (f32x4) slot in the row

    int start, end;
    if constexpr (MODE == 2) {
        int lo = 0, hi = n_edges;
        while (lo < hi) { int mid = (lo + hi) >> 1; if (rows[mid] < node) lo = mid + 1; else hi = mid; }
        start = lo; hi = n_edges;
        while (lo < hi) { int mid = (lo + hi) >> 1; if (rows[mid] <= node) lo = mid + 1; else hi = mid; }
        end = lo;
    } else {
        start = row_ptr[node];
        end   = row_ptr[node + 1];
    }

    const float4* __restrict__ x4 = reinterpret_cast<const float4*>(xf);

    float ax = 0.f, ay = 0.f, az = 0.f, aw = 0.f;

    for (int base = start; base < end; base += 64) {
        const int navail = min(64, end - base);
        const int idx = base + lane;
        if (lane < navail) {
            s_c[wv][lane] = LDNT(cols + idx);
            s_v[wv][lane] = LDNT(vals + idx);
        }
        // Same-wave LDS write->read is in-order in HW; no barrier needed
        // (each wave touches only its own slice).

        int j = 0;
        // Big: 8 pair-steps per iter -> 8 gathers in flight per half, 16 edges.
        for (; j + 15 < navail; j += 16) {
            int c[8]; float v[8];
            #pragma unroll
            for (int k = 0; k < 8; ++k) {
                c[k] = s_c[wv][j + 2 * k + half];
                v[k] = s_v[wv][j + 2 * k + half];
            }
            if constexpr (MODE == 0) {
                ushort4 r[8];
                #pragma unroll
                for (int k = 0; k < 8; ++k) r[k] = xh[(size_t)c[k] * 32 + l32];
                #pragma unroll
                for (int k = 0; k < 8; ++k) {
                    ax = fmaf(v[k], h2f(r[k].x), ax); ay = fmaf(v[k], h2f(r[k].y), ay);
                    az = fmaf(v[k], h2f(r[k].z), az); aw = fmaf(v[k], h2f(r[k].w), aw);
                }
            } else {
                float4 r[8];
                #pragma unroll
                for (int k = 0; k < 8; ++k) r[k] = x4[(size_t)c[k] * 32 + l32];
                #pragma unroll
                for (int k = 0; k < 8; ++k) {
                    ax = fmaf(v[k], r[k].x, ax); ay = fmaf(v[k], r[k].y, ay);
                    az = fmaf(v[k], r[k].z, az); aw = fmaf(v[k], r[k].w, aw);
                }
            }
        }
        // Mid: 4 pair-steps (4 gathers in flight per half, 8 edges).
        for (; j + 7 < navail; j += 8) {
            int   c0 = s_c[wv][j + 0 + half]; float v0 = s_v[wv][j + 0 + half];
            int   c1 = s_c[wv][j + 2 + half]; float v1 = s_v[wv][j + 2 + half];
            int   c2 = s_c[wv][j + 4 + half]; float v2 = s_v[wv][j + 4 + half];
            int   c3 = s_c[wv][j + 6 + half]; float v3 = s_v[wv][j + 6 + half];
            if constexpr (MODE == 0) {
                ushort4 r0 = xh[(size_t)c0 * 32 + l32];
                ushort4 r1 = xh[(size_t)c1 * 32 + l32];
                ushort4 r2 = xh[(size_t)c2 * 32 + l32];
                ushort4 r3 = xh[(size_t)c3 * 32 + l32];
                ax = fmaf(v0, h2f(r0.x), ax); ay = fmaf(v0, h2f(r0.y), ay);
                az = fmaf(v0, h2f(r0.z), az); aw = fmaf(v0, h2f(r0.w), aw);
                ax = fmaf(v1, h2f(r1.x), ax); ay = fmaf(v1, h2f(r1.y), ay);
                az = fmaf(v1, h2f(r1.z), az); aw = fmaf(v1, h2f(r1.w), aw);
                ax = fmaf(v2, h2f(r2.x), ax); ay = fmaf(v2, h2f(r2.y), ay);
                az = fmaf(v2, h2f(r2.z), az); aw = fmaf(v2, h2f(r2.w), aw);
                ax = fmaf(v3, h2f(r3.x), ax); ay = fmaf(v3, h2f(r3.y), ay);
                az = fmaf(v3, h2f(r3.z), az); aw = fmaf(v3, h2f(r3.w), aw);
            } else {
                float4 r0 = x4[(size_t)c0 * 32 + l32];
                float4 r1 = x4[(size_t)c1 * 32 + l32];
                float4 r2 = x4[(size_t)c2 * 32 + l32];
                float4 r3 = x4[(size_t)c3 * 32 + l32];
                ax = fmaf(v0, r0.x, ax); ay = fmaf(v0, r0.y, ay);
                az = fmaf(v0, r0.z, az); aw = fmaf(v0, r0.w, aw);
                ax = fmaf(v1, r1.x, ax); ay = fmaf(v1, r1.y, ay);
                az = fmaf(v1, r1.z, az); aw = fmaf(v1, r1.w, aw);
                ax = fmaf(v2, r2.x, ax); ay = fmaf(v2, r2.y, ay);
                az = fmaf(v2, r2.z, az); aw = fmaf(v2, r2.w, aw);
                ax = fmaf(v3, r3.x, ax); ay = fmaf(v3, r3.y, ay);
                az = fmaf(v3, r3.z, az); aw = fmaf(v3, r3.w, aw);
            }
        }
        // Pair tail.
        for (; j + 1 < navail; j += 2) {
            int   c0 = s_c[wv][j + half];
            float v0 = s_v[wv][j + half];
            if constexpr (MODE == 0) {
                ushort4 r0 = xh[(size_t)c0 * 32 + l32];
                ax = fmaf(v0, h2f(r0.x), ax); ay = fmaf(v0, h2f(r0.y), ay);
                az = fmaf(v0, h2f(r0.z), az); aw = fmaf(v0, h2f(r0.w), aw);
            } else {
                float4 r0 = x4[(size_t)c0 * 32 + l32];
                ax = fmaf(v0, r0.x, ax); ay = fmaf(v0, r0.y, ay);
                az = fmaf(v0, r0.z, az); aw = fmaf(v0, r0.w, aw);
            }
        }
        // Odd last edge: only lower half contributes (v=0 on upper half).
        if (j < navail) {
            int   c0 = s_c[wv][j];
            float v0 = half ? 0.f : s_v[wv][j];
            if constexpr (MODE == 0) {
                ushort4 r0 = xh[(size_t)c0 * 32 + l32];
                ax = fmaf(v0, h2f(r0.x), ax); ay = fmaf(v0, h2f(r0.y), ay);
                az = fmaf(v0, h2f(r0.z), az); aw = fmaf(v0, h2f(r0.w), aw);
            } else {
                float4 r0 = x4[(size_t)c0 * 32 + l32];
                ax = fmaf(v0, r0.x, ax); ay = fmaf(v0, r0.y, ay);
                az = fmaf(v0, r0.z, az); aw = fmaf(v0, r0.w, aw);
            }
        }
    }

    // Combine even/odd halves (lane i and i+32 hold the same feature slots).
    ax += __shfl_xor(ax, 32, 64);
    ay += __shfl_xor(ay, 32, 64);
    az += __shfl_xor(az, 32, 64);
    aw += __shfl_xor(aw, 32, 64);

    // Norm^2 across the 32-lane group.
    float nrm2 = fmaf(ax, ax, fmaf(ay, ay, fmaf(az, az, aw * aw)));
    #pragma unroll
    for (int off = 16; off > 0; off >>= 1) nrm2 += __shfl_xor(nrm2, off, 64);

    // expmap0 (sqrt_c=1): y = tanh(||u||)/||u|| * u;  proj uses ||y||==tanh(||u||).
    float u_norm = fmaxf(sqrtf(nrm2), MIN_NORM);
    float t = tanhf(u_norm);
    float scale = t / u_norm;
    const float maxnorm = 1.0f - PROJ_EPS;
    if (t > maxnorm) scale *= maxnorm / t;

    if (half == 0) {
        floatx4 y;
        y.x = scale * ax; y.y = scale * ay; y.z = scale * az; y.w = scale * aw;
        __builtin_nontemporal_store(y, reinterpret_cast<floatx4*>(out + (size_t)node * 128) + l32);
    }
}

extern "C" void kernel_launch(void* const* d_in, const int* in_sizes, int n_in,
                              void* d_out, int out_size, void* d_ws, size_t ws_size,
                              hipStream_t stream) {
    const float* x    = (const float*)d_in[0];
    const float* vals = (const float*)d_in[1];
    const int*   rows = (const int*)d_in[2];
    const int*   cols = (const int*)d_in[3];
    float* out = (float*)d_out;

    const int d_feat  = 128;
    const int n_nodes = in_sizes[0] / d_feat;
    const int n_edges = in_sizes[1];

    char* ws = (char*)d_ws;
    const size_t rp_bytes = (((size_t)(n_nodes + 1) * sizeof(int)) + 255) & ~(size_t)255;
    const size_t xh_bytes = (size_t)n_nodes * d_feat * sizeof(unsigned short);

    int*     row_ptr = nullptr;
    ushort4* xh      = nullptr;

    if (ws && ws_size >= rp_bytes + xh_bytes) {
        row_ptr = (int*)ws;
        xh      = (ushort4*)(ws + rp_bytes);
        {
            const int b = 256, g = (n_edges + b - 1) / b;
            build_rowptr_kernel<<<g, b, 0, stream>>>(rows, row_ptr, n_nodes, n_edges);
        }
        {
            const int n4 = n_nodes * (d_feat / 4);
            const int b = 256, g = (n4 + b - 1) / b;
            cvt_f32_to_f16<<<g, b, 0, stream>>>(reinterpret_cast<const float4*>(x),
                                                reinterpret_cast<uint2*>(xh), n4);
        }
    }

    const int block = 256;                 // 4 waves/block, 1 node per wave
    const int waves_per_block = block / 64;
    const int grid = (n_nodes + waves_per_block - 1) / waves_per_block;

    if (xh) {
        hyp_agg_kernel<0><<<grid, block, 0, stream>>>(x, xh, vals, rows, cols, row_ptr,
                                                      out, n_nodes, n_edges);
    } else {
        hyp_agg_kernel<2><<<grid, block, 0, stream>>>(x, nullptr, vals, rows, cols, nullptr,
                                                      out, n_nodes, n_edges);
    }
}

// Round 10
// 118.258 us; speedup vs baseline: 1.0206x; 1.0206x over previous
//
#include <hip/hip_runtime.h>
#include <hip/hip_fp16.h>

// HyperbolicAggregation: out = proj(expmap0(A @ x, c=1), c=1)
// A sparse (rows sorted), x [50000,128] f32.
// Kernel 0: x f32 -> f16 into d_ws (halves gather traffic; row = 256 B).
// Kernel 1: O(E) coalesced row_ptr build -> d_ws.
// Kernel 2: one wave per node, QUARTER-WAVE gathers: 16 lanes x 16 B (f16x8)
//           cover one full row -> 4 edges per gather instruction. Edge
//           cols/vals staged per-chunk in the wave's LDS slice. Ladder
//           16/4/tail edges (4 gathers in flight). 8 f32 accumulators/lane;
//           cross-quarter reduce via shfl_xor(16,32); 16-lane norm butterfly.

#define MIN_NORM 1e-15f
#define PROJ_EPS 4e-3f

#define LDNT(p) __builtin_nontemporal_load(p)

typedef float floatx4 __attribute__((ext_vector_type(4)));

__device__ inline float h2f(unsigned short u) {
    __half h;
    __builtin_memcpy(&h, &u, sizeof(h));
    return __half2float(h);
}

__global__ __launch_bounds__(256) void cvt_f32_to_f16(
    const float4* __restrict__ x4, uint2* __restrict__ xh, int n4)
{
    int i = blockIdx.x * blockDim.x + threadIdx.x;
    if (i >= n4) return;
    float4 a = x4[i];
    __half2 lo = __floats2half2_rn(a.x, a.y);
    __half2 hi = __floats2half2_rn(a.z, a.w);
    uint2 o;
    o.x = *reinterpret_cast<unsigned int*>(&lo);
    o.y = *reinterpret_cast<unsigned int*>(&hi);
    xh[i] = o;
}

__global__ __launch_bounds__(256) void build_rowptr_kernel(
    const int* __restrict__ rows, int* __restrict__ row_ptr,
    int n_nodes, int n_edges)
{
    int e = blockIdx.x * blockDim.x + threadIdx.x;
    if (e >= n_edges) return;
    int r = rows[e];
    int prev = (e == 0) ? -1 : rows[e - 1];
    for (int node = prev + 1; node <= r; ++node) row_ptr[node] = e;
    if (e == n_edges - 1) {
        for (int node = r + 1; node <= n_nodes; ++node) row_ptr[node] = n_edges;
    }
}

__device__ inline void acc8(float v, const uint4& r, float* a) {
    a[0] = fmaf(v, h2f((unsigned short)(r.x & 0xffff)), a[0]);
    a[1] = fmaf(v, h2f((unsigned short)(r.x >> 16)),    a[1]);
    a[2] = fmaf(v, h2f((unsigned short)(r.y & 0xffff)), a[2]);
    a[3] = fmaf(v, h2f((unsigned short)(r.y >> 16)),    a[3]);
    a[4] = fmaf(v, h2f((unsigned short)(r.z & 0xffff)), a[4]);
    a[5] = fmaf(v, h2f((unsigned short)(r.z >> 16)),    a[5]);
    a[6] = fmaf(v, h2f((unsigned short)(r.w & 0xffff)), a[6]);
    a[7] = fmaf(v, h2f((unsigned short)(r.w >> 16)),    a[7]);
}

// MODE 0: f16 x (ws) + row_ptr, quarter-wave.  MODE 2: f32 x + bsearch fallback.
template <int MODE>
__global__ __launch_bounds__(256) void hyp_agg_kernel(
    const float* __restrict__ xf,
    const unsigned short* __restrict__ xh,
    const float* __restrict__ vals,
    const int* __restrict__ rows,
    const int* __restrict__ cols,
    const int* __restrict__ row_ptr,
    float* __restrict__ out,
    int n_nodes, int n_edges)
{
    __shared__ int   s_c[4][64];
    __shared__ float s_v[4][64];

    const int tid  = threadIdx.x;
    const int node = (int)((blockIdx.x * blockDim.x + tid) >> 6);
    if (node >= n_nodes) return;
    const int wv   = tid >> 6;     // wave within block (own LDS slice)
    const int lane = tid & 63;

    if constexpr (MODE == 0) {
        const int q   = lane >> 4;   // quarter 0-3: edge j+q
        const int l16 = lane & 15;   // 16-B chunk within the 256-B row

        const int start = row_ptr[node];
        const int end   = row_ptr[node + 1];

        float a[8] = {0.f, 0.f, 0.f, 0.f, 0.f, 0.f, 0.f, 0.f};

        for (int base = start; base < end; base += 64) {
            const int navail = min(64, end - base);
            const int idx = base + lane;
            if (lane < navail) {
                s_c[wv][lane] = LDNT(cols + idx);
                s_v[wv][lane] = LDNT(vals + idx);
            }
            // Same-wave LDS write->read is in-order; wave-private slice.

            int j = 0;
            // Big: 4 quad-steps -> 4 gathers in flight, 16 edges per iter.
            for (; j + 15 < navail; j += 16) {
                int   c0 = s_c[wv][j +  0 + q]; float v0 = s_v[wv][j +  0 + q];
                int   c1 = s_c[wv][j +  4 + q]; float v1 = s_v[wv][j +  4 + q];
                int   c2 = s_c[wv][j +  8 + q]; float v2 = s_v[wv][j +  8 + q];
                int   c3 = s_c[wv][j + 12 + q]; float v3 = s_v[wv][j + 12 + q];
                uint4 r0 = reinterpret_cast<const uint4*>(xh + (size_t)c0 * 128)[l16];
                uint4 r1 = reinterpret_cast<const uint4*>(xh + (size_t)c1 * 128)[l16];
                uint4 r2 = reinterpret_cast<const uint4*>(xh + (size_t)c2 * 128)[l16];
                uint4 r3 = reinterpret_cast<const uint4*>(xh + (size_t)c3 * 128)[l16];
                acc8(v0, r0, a); acc8(v1, r1, a); acc8(v2, r2, a); acc8(v3, r3, a);
            }
            // Mid: one quad-step (4 edges).
            for (; j + 3 < navail; j += 4) {
                int   c0 = s_c[wv][j + q];
                float v0 = s_v[wv][j + q];
                uint4 r0 = reinterpret_cast<const uint4*>(xh + (size_t)c0 * 128)[l16];
                acc8(v0, r0, a);
            }
            // Tail: 1-3 edges; inactive quarters contribute v=0 (safe col).
            if (j < navail) {
                const bool act = (j + q) < navail;
                int   c0 = s_c[wv][act ? (j + q) : j];
                float v0 = act ? s_v[wv][j + q] : 0.f;
                uint4 r0 = reinterpret_cast<const uint4*>(xh + (size_t)c0 * 128)[l16];
                acc8(v0, r0, a);
            }
        }

        // Combine quarters: xor 16 merges q0<->q1,q2<->q3; xor 32 merges halves.
        #pragma unroll
        for (int t = 0; t < 8; ++t) a[t] += __shfl_xor(a[t], 16, 64);
        #pragma unroll
        for (int t = 0; t < 8; ++t) a[t] += __shfl_xor(a[t], 32, 64);

        // Norm^2: per-lane partial over its 8 features, butterfly over 16 lanes.
        float nrm2 = 0.f;
        #pragma unroll
        for (int t = 0; t < 8; ++t) nrm2 = fmaf(a[t], a[t], nrm2);
        #pragma unroll
        for (int off = 8; off > 0; off >>= 1) nrm2 += __shfl_xor(nrm2, off, 64);

        float u_norm = fmaxf(sqrtf(nrm2), MIN_NORM);
        float t = tanhf(u_norm);
        float scale = t / u_norm;
        const float maxnorm = 1.0f - PROJ_EPS;
        if (t > maxnorm) scale *= maxnorm / t;

        if (q == 0) {
            floatx4 y0, y1;
            y0.x = scale * a[0]; y0.y = scale * a[1]; y0.z = scale * a[2]; y0.w = scale * a[3];
            y1.x = scale * a[4]; y1.y = scale * a[5]; y1.z = scale * a[6]; y1.w = scale * a[7];
            floatx4* p = reinterpret_cast<floatx4*>(out + (size_t)node * 128) + l16 * 2;
            __builtin_nontemporal_store(y0, p);
            __builtin_nontemporal_store(y1, p + 1);
        }
        return;
    }

    // ---- MODE 2 fallback: f32 x, inline binary search, half-wave float4 ----
    const int half = lane >> 5;
    const int l32  = lane & 31;
    int lo = 0, hi = n_edges;
    while (lo < hi) { int mid = (lo + hi) >> 1; if (rows[mid] < node) lo = mid + 1; else hi = mid; }
    int start = lo; hi = n_edges;
    while (lo < hi) { int mid = (lo + hi) >> 1; if (rows[mid] <= node) lo = mid + 1; else hi = mid; }
    int end = lo;

    const float4* __restrict__ x4 = reinterpret_cast<const float4*>(xf);
    float ax = 0.f, ay = 0.f, az = 0.f, aw = 0.f;

    for (int base = start; base < end; base += 64) {
        const int navail = min(64, end - base);
        const int idx = base + lane;
        if (lane < navail) {
            s_c[wv][lane] = LDNT(cols + idx);
            s_v[wv][lane] = LDNT(vals + idx);
        }
        int j = 0;
        for (; j + 1 < navail; j += 2) {
            int   c0 = s_c[wv][j + half];
            float v0 = s_v[wv][j + half];
            float4 r0 = x4[(size_t)c0 * 32 + l32];
            ax = fmaf(v0, r0.x, ax); ay = fmaf(v0, r0.y, ay);
            az = fmaf(v0, r0.z, az); aw = fmaf(v0, r0.w, aw);
        }
        if (j < navail) {
            int   c0 = s_c[wv][j];
            float v0 = half ? 0.f : s_v[wv][j];
            float4 r0 = x4[(size_t)c0 * 32 + l32];
            ax = fmaf(v0, r0.x, ax); ay = fmaf(v0, r0.y, ay);
            az = fmaf(v0, r0.z, az); aw = fmaf(v0, r0.w, aw);
        }
    }

    ax += __shfl_xor(ax, 32, 64);
    ay += __shfl_xor(ay, 32, 64);
    az += __shfl_xor(az, 32, 64);
    aw += __shfl_xor(aw, 32, 64);

    float nrm2 = fmaf(ax, ax, fmaf(ay, ay, fmaf(az, az, aw * aw)));
    #pragma unroll
    for (int off = 16; off > 0; off >>= 1) nrm2 += __shfl_xor(nrm2, off, 64);

    float u_norm = fmaxf(sqrtf(nrm2), MIN_NORM);
    float t = tanhf(u_norm);
    float scale = t / u_norm;
    const float maxnorm = 1.0f - PROJ_EPS;
    if (t > maxnorm) scale *= maxnorm / t;

    if (half == 0) {
        floatx4 y;
        y.x = scale * ax; y.y = scale * ay; y.z = scale * az; y.w = scale * aw;
        __builtin_nontemporal_store(y, reinterpret_cast<floatx4*>(out + (size_t)node * 128) + l32);
    }
}

extern "C" void kernel_launch(void* const* d_in, const int* in_sizes, int n_in,
                              void* d_out, int out_size, void* d_ws, size_t ws_size,
                              hipStream_t stream) {
    const float* x    = (const float*)d_in[0];
    const float* vals = (const float*)d_in[1];
    const int*   rows = (const int*)d_in[2];
    const int*   cols = (const int*)d_in[3];
    float* out = (float*)d_out;

    const int d_feat  = 128;
    const int n_nodes = in_sizes[0] / d_feat;
    const int n_edges = in_sizes[1];

    char* ws = (char*)d_ws;
    const size_t rp_bytes = (((size_t)(n_nodes + 1) * sizeof(int)) + 255) & ~(size_t)255;
    const size_t xh_bytes = (size_t)n_nodes * d_feat * sizeof(unsigned short);

    int*            row_ptr = nullptr;
    unsigned short* xh      = nullptr;

    if (ws && ws_size >= rp_bytes + xh_bytes) {
        row_ptr = (int*)ws;
        xh      = (unsigned short*)(ws + rp_bytes);
        {
            const int b = 256, g = (n_edges + b - 1) / b;
            build_rowptr_kernel<<<g, b, 0, stream>>>(rows, row_ptr, n_nodes, n_edges);
        }
        {
            const int n4 = n_nodes * (d_feat / 4);
            const int b = 256, g = (n4 + b - 1) / b;
            cvt_f32_to_f16<<<g, b, 0, stream>>>(reinterpret_cast<const float4*>(x),
                                                reinterpret_cast<uint2*>(xh), n4);
        }
    }

    const int block = 256;                 // 4 waves/block, 1 node per wave
    const int waves_per_block = block / 64;
    const int grid = (n_nodes + waves_per_block - 1) / waves_per_block;

    if (xh) {
        hyp_agg_kernel<0><<<grid, block, 0, stream>>>(x, xh, vals, rows, cols, row_ptr,
                                                      out, n_nodes, n_edges);
    } else {
        hyp_agg_kernel<2><<<grid, block, 0, stream>>>(x, nullptr, vals, rows, cols, nullptr,
                                                      out, n_nodes, n_edges);
    }
}